// Round 2
// baseline (2755.629 us; speedup 1.0000x reference)
//
#include <hip/hip_runtime.h>
#include <math.h>

#define NN 100000
#define NE 3200000
#define ENB 16   // nodes per block in encoder

__device__ __forceinline__ float selu_f(float x) {
    const float a = 1.6732632423543772f;
    const float s = 1.0507009873554805f;
    return x > 0.f ? s * x : s * a * (__expf(x) - 1.f);
}
__device__ __forceinline__ float lrelu02(float x)  { return fmaxf(x, 0.2f * x); }
__device__ __forceinline__ float lrelu001(float x) { return fmaxf(x, 0.01f * x); }

// ---------------- encoder: x0 -> x1 -> xl1 (+att1 sums). x0/x1 never hit HBM ----
__global__ __launch_bounds__(256) void k_enc(
    const float* __restrict__ des, const float* __restrict__ tweet,
    const float* __restrict__ nprop, const float* __restrict__ cprop,
    const float* __restrict__ Wd, const float* __restrict__ bd,
    const float* __restrict__ Wt, const float* __restrict__ bt,
    const float* __restrict__ Wn, const float* __restrict__ bn,
    const float* __restrict__ Wc, const float* __restrict__ bc,
    const float* __restrict__ Wi, const float* __restrict__ bi,
    const float* __restrict__ W1, const float* __restrict__ a1s,
    const float* __restrict__ a1d,
    float* __restrict__ xl1, float* __restrict__ as1, float* __restrict__ ad1)
{
    __shared__ float x0[ENB][128];
    __shared__ float x1s[ENB][128];
    __shared__ float ps[ENB][128], pd[ENB][128];

    const int t = threadIdx.x;

    // ---- phase A: x0 = concat of 4 selu(linear); 16 threads per node ----
    {
        const int n = t >> 4;          // local node 0..15
        const int sub = t & 15;        // 0..15
        const int node = blockIdx.x * ENB + n;
        const float* drow = des + (size_t)node * 768;
        const float* trow = tweet + (size_t)node * 768;
        float aD0 = 0.f, aD1 = 0.f, aT0 = 0.f, aT1 = 0.f;
        for (int k = 0; k < 768; k += 4) {
            const float4 dv = *reinterpret_cast<const float4*>(drow + k);
            const float4 tv = *reinterpret_cast<const float4*>(trow + k);
            const float* wd = Wd + k * 32 + sub;
            const float* wt = Wt + k * 32 + sub;
            aD0 = fmaf(dv.x, wd[0],   aD0);  aD1 = fmaf(dv.x, wd[16],  aD1);
            aD0 = fmaf(dv.y, wd[32],  aD0);  aD1 = fmaf(dv.y, wd[48],  aD1);
            aD0 = fmaf(dv.z, wd[64],  aD0);  aD1 = fmaf(dv.z, wd[80],  aD1);
            aD0 = fmaf(dv.w, wd[96],  aD0);  aD1 = fmaf(dv.w, wd[112], aD1);
            aT0 = fmaf(tv.x, wt[0],   aT0);  aT1 = fmaf(tv.x, wt[16],  aT1);
            aT0 = fmaf(tv.y, wt[32],  aT0);  aT1 = fmaf(tv.y, wt[48],  aT1);
            aT0 = fmaf(tv.z, wt[64],  aT0);  aT1 = fmaf(tv.z, wt[80],  aT1);
            aT0 = fmaf(tv.w, wt[96],  aT0);  aT1 = fmaf(tv.w, wt[112], aT1);
        }
        float aN0 = 0.f, aN1 = 0.f, aC0 = 0.f, aC1 = 0.f;
        const float* nr = nprop + (size_t)node * 5;
        for (int k = 0; k < 5; ++k) {
            aN0 = fmaf(nr[k], Wn[k * 32 + sub],      aN0);
            aN1 = fmaf(nr[k], Wn[k * 32 + sub + 16], aN1);
        }
        const float* cr = cprop + (size_t)node * 3;
        for (int k = 0; k < 3; ++k) {
            aC0 = fmaf(cr[k], Wc[k * 32 + sub],      aC0);
            aC1 = fmaf(cr[k], Wc[k * 32 + sub + 16], aC1);
        }
        x0[n][sub]          = selu_f(aD0 + bd[sub]);
        x0[n][sub + 16]     = selu_f(aD1 + bd[sub + 16]);
        x0[n][32 + sub]     = selu_f(aT0 + bt[sub]);
        x0[n][32 + sub + 16]= selu_f(aT1 + bt[sub + 16]);
        x0[n][64 + sub]     = selu_f(aN0 + bn[sub]);
        x0[n][64 + sub + 16]= selu_f(aN1 + bn[sub + 16]);
        x0[n][96 + sub]     = selu_f(aC0 + bc[sub]);
        x0[n][96 + sub + 16]= selu_f(aC1 + bc[sub + 16]);
    }
    __syncthreads();

    const int c  = t & 127;
    const int nb = (t >> 7) * 8;     // 8 nodes per thread-half

    // ---- phase B: x1 = selu(x0 @ Wi + bi) ----
    {
        float acc[8];
#pragma unroll
        for (int j = 0; j < 8; ++j) acc[j] = 0.f;
        for (int k = 0; k < 128; ++k) {
            const float w = Wi[k * 128 + c];
#pragma unroll
            for (int j = 0; j < 8; ++j) acc[j] = fmaf(x0[nb + j][k], w, acc[j]);
        }
        const float b = bi[c];
#pragma unroll
        for (int j = 0; j < 8; ++j) x1s[nb + j][c] = selu_f(acc[j] + b);
    }
    __syncthreads();

    // ---- phase C: xl1 = x1 @ W1, attention partial products ----
    {
        float acc[8];
#pragma unroll
        for (int j = 0; j < 8; ++j) acc[j] = 0.f;
        for (int k = 0; k < 128; ++k) {
            const float w = W1[k * 128 + c];
#pragma unroll
            for (int j = 0; j < 8; ++j) acc[j] = fmaf(x1s[nb + j][k], w, acc[j]);
        }
        const float vs = a1s[c], vd = a1d[c];
#pragma unroll
        for (int j = 0; j < 8; ++j) {
            const size_t node = (size_t)blockIdx.x * ENB + nb + j;
            xl1[node * 128 + c] = acc[j];
            ps[nb + j][c] = acc[j] * vs;
            pd[nb + j][c] = acc[j] * vd;
        }
    }
    __syncthreads();

    if (t < 128) {                   // 16 nodes x 4 heads x {s,d}
        const int n2 = t >> 3, h = (t >> 1) & 3, w = t & 1;
        const int node = blockIdx.x * ENB + n2;
        const float* pp = w ? pd[n2] : ps[n2];
        const int j0 = t & 31;       // stagger to avoid bank conflicts
        float sum = 0.f;
        for (int i = 0; i < 32; ++i) sum += pp[h * 32 + ((j0 + i) & 31)];
        if (w) ad1[node * 4 + h] = sum; else as1[node * 4 + h] = sum;
    }
}

// ---------------- CSR build ----------------
__global__ __launch_bounds__(256) void k_deg(const int* __restrict__ dst, int* __restrict__ deg) {
    const int e = blockIdx.x * 256 + threadIdx.x;
    if (e < NE) atomicAdd(&deg[dst[e]], 1);
}

// tiled shuffle-scan, one block
__global__ __launch_bounds__(1024) void k_scan(const int* __restrict__ deg,
                                               int* __restrict__ rowptr, int* __restrict__ cursor) {
    __shared__ int wsum[16];
    __shared__ int carry;
    const int t = threadIdx.x;
    const int lane = t & 63, wv = t >> 6;
    if (t == 0) carry = 0;
    __syncthreads();
    for (int base = 0; base < NN; base += 1024) {
        const int i = base + t;
        const int v = (i < NN) ? deg[i] : 0;
        int x = v;
#pragma unroll
        for (int off = 1; off < 64; off <<= 1) {
            const int u = __shfl_up(x, off, 64);
            if (lane >= off) x += u;
        }
        if (lane == 63) wsum[wv] = x;
        __syncthreads();
        if (wv == 0) {
            int y = (lane < 16) ? wsum[lane] : 0;
#pragma unroll
            for (int off = 1; off < 16; off <<= 1) {
                const int u = __shfl_up(y, off, 64);
                if (lane >= off) y += u;
            }
            if (lane < 16) wsum[lane] = y;
        }
        __syncthreads();
        const int wbase = (wv == 0) ? 0 : wsum[wv - 1];
        const int excl = carry + wbase + (x - v);
        if (i < NN) { rowptr[i] = excl; cursor[i] = excl; }
        __syncthreads();
        if (t == 0) carry += wsum[15];
        __syncthreads();
    }
    if (t == 0) rowptr[NN] = carry;
}

__global__ __launch_bounds__(256) void k_fill(const int* __restrict__ src, const int* __restrict__ dst,
                                              int* __restrict__ cursor, int* __restrict__ csr) {
    const int e = blockIdx.x * 256 + threadIdx.x;
    if (e < NE) {
        const int pos = atomicAdd(&cursor[dst[e]], 1);
        csr[pos] = src[e];
    }
}

// ---------------- GAT1 aggregate (4 heads, online softmax) + fused xl2 = x2@W2 ----
__global__ __launch_bounds__(256) void k_gat1(
    const float* __restrict__ xl, const float* __restrict__ as_,
    const float* __restrict__ ad_, const float* __restrict__ b1,
    const int* __restrict__ rowptr, const int* __restrict__ csr,
    const float* __restrict__ W2, const float* __restrict__ a2s, const float* __restrict__ a2d,
    float* __restrict__ xl2, float* __restrict__ as2, float* __restrict__ ad2)
{
    __shared__ float xs[4][128];
    __shared__ float ps[4][128], pd[4][128];
    const int t = threadIdx.x;
    const int wv = t >> 6, lane = t & 63;
    const int d = blockIdx.x * 4 + wv;
    const int c0 = lane * 2;
    const int h = c0 >> 5;                      // head of both my channels

    const float adv = ad_[d * 4 + h];
    const float a_self = lrelu02(as_[d * 4 + h] + adv);
    const int beg = rowptr[d], end = rowptr[d + 1];

    // online softmax, self-loop seeds the state
    float m = a_self, z = 1.f;
    const float2 xv = *reinterpret_cast<const float2*>(xl + (size_t)d * 128 + c0);
    float acc0 = xv.x, acc1 = xv.y;
#pragma unroll 2
    for (int i = beg; i < end; ++i) {
        const int s = csr[i];
        const float a = lrelu02(as_[s * 4 + h] + adv);
        const float mn = fmaxf(m, a);
        const float sc = __expf(m - mn);
        const float e  = __expf(a - mn);
        const float2 v = *reinterpret_cast<const float2*>(xl + (size_t)s * 128 + c0);
        z    = fmaf(z, sc, e);
        acc0 = fmaf(acc0, sc, e * v.x);
        acc1 = fmaf(acc1, sc, e * v.y);
        m = mn;
    }
    const float inv = 1.f / z;
    xs[wv][c0]     = acc0 * inv + b1[c0];
    xs[wv][c0 + 1] = acc1 * inv + b1[c0 + 1];
    __syncthreads();

    // fused: xl2 = x2 @ W2, attention products (1 head, 128 ch)
    const int base = blockIdx.x * 4;
    for (int p = 0; p < 2; ++p) {
        const int idx = p * 256 + t;
        const int n = idx >> 7, cc = idx & 127;
        float acc = 0.f;
        for (int k = 0; k < 128; k += 4) {
            acc = fmaf(xs[n][k + 0], W2[(k + 0) * 128 + cc], acc);
            acc = fmaf(xs[n][k + 1], W2[(k + 1) * 128 + cc], acc);
            acc = fmaf(xs[n][k + 2], W2[(k + 2) * 128 + cc], acc);
            acc = fmaf(xs[n][k + 3], W2[(k + 3) * 128 + cc], acc);
        }
        xl2[(size_t)(base + n) * 128 + cc] = acc;
        ps[n][cc] = acc * a2s[cc];
        pd[n][cc] = acc * a2d[cc];
    }
    __syncthreads();
    if (t < 8) {                     // 4 nodes x {s,d}
        const int n = t >> 1, w = t & 1;
        const float* pp = w ? pd[n] : ps[n];
        float sum = 0.f;
        for (int j = 0; j < 128; ++j) sum += pp[j];
        if (w) ad2[base + n] = sum; else as2[base + n] = sum;
    }
}

// ---------------- GAT2 aggregate (1 head, online softmax) -> x3 ----------------
__global__ __launch_bounds__(256) void k_gat2(
    const float* __restrict__ xl, const float* __restrict__ as_,
    const float* __restrict__ ad_, const float* __restrict__ b2,
    const int* __restrict__ rowptr, const int* __restrict__ csr,
    float* __restrict__ x3)
{
    const int t = threadIdx.x;
    const int wv = t >> 6, lane = t & 63;
    const int d = blockIdx.x * 4 + wv;
    const int c0 = lane * 2;

    const float adv = ad_[d];
    const float a_self = lrelu02(as_[d] + adv);
    const int beg = rowptr[d], end = rowptr[d + 1];

    float m = a_self, z = 1.f;
    const float2 xv = *reinterpret_cast<const float2*>(xl + (size_t)d * 128 + c0);
    float acc0 = xv.x, acc1 = xv.y;
#pragma unroll 2
    for (int i = beg; i < end; ++i) {
        const int s = csr[i];
        const float a = lrelu02(as_[s] + adv);
        const float mn = fmaxf(m, a);
        const float sc = __expf(m - mn);
        const float e  = __expf(a - mn);
        const float2 v = *reinterpret_cast<const float2*>(xl + (size_t)s * 128 + c0);
        z    = fmaf(z, sc, e);
        acc0 = fmaf(acc0, sc, e * v.x);
        acc1 = fmaf(acc1, sc, e * v.y);
        m = mn;
    }
    const float inv = 1.f / z;
    float2 o;
    o.x = acc0 * inv + b2[c0];
    o.y = acc1 * inv + b2[c0 + 1];
    *reinterpret_cast<float2*>(x3 + (size_t)d * 128 + c0) = o;
}

// ---------------- MoE: top-1 gate == argmax; expert MLP ----------------
__global__ __launch_bounds__(256) void k_moe(
    const float* __restrict__ x, const float* __restrict__ Wg,
    const float* __restrict__ We1, const float* __restrict__ be1,
    const float* __restrict__ We2, const float* __restrict__ be2,
    float* __restrict__ out)
{
    __shared__ float xs[16][128];
    __shared__ float hs[16][128];
    __shared__ int sel[16];
    const int t = threadIdx.x;
    const int base = blockIdx.x * 16;

    for (int i = t; i < 16 * 128; i += 256) {
        const int n = i >> 7, cc = i & 127;
        xs[n][cc] = x[(size_t)(base + n) * 128 + cc];
    }
    __syncthreads();
    if (t < 16) {
        float g0 = 0.f, g1 = 0.f;
        for (int k = 0; k < 128; ++k) {
            g0 = fmaf(xs[t][k], Wg[k * 2 + 0], g0);
            g1 = fmaf(xs[t][k], Wg[k * 2 + 1], g1);
        }
        sel[t] = (g1 > g0) ? 1 : 0;    // ties -> expert 0 (top_k picks first)
    }
    __syncthreads();

    const int half = t >> 7, cc = t & 127;
    const int n0 = half * 8;
    float acc[8];
#pragma unroll
    for (int i = 0; i < 8; ++i) acc[i] = 0.f;
    for (int k = 0; k < 128; ++k) {
        const float w0 = We1[k * 128 + cc];
        const float w1 = We1[128 * 128 + k * 128 + cc];
#pragma unroll
        for (int i = 0; i < 8; ++i) {
            const float w = sel[n0 + i] ? w1 : w0;
            acc[i] = fmaf(xs[n0 + i][k], w, acc[i]);
        }
    }
#pragma unroll
    for (int i = 0; i < 8; ++i) {
        const int e = sel[n0 + i];
        hs[n0 + i][cc] = lrelu001(acc[i] + be1[e * 128 + cc]);
    }
    __syncthreads();
    if (t < 32) {
        const int n = t >> 1, j = t & 1;
        const int e = sel[n];
        float o = 0.f;
        for (int k = 0; k < 128; ++k) o = fmaf(hs[n][k], We2[e * 256 + k * 2 + j], o);
        out[(size_t)(base + n) * 2 + j] = o + be2[e * 2 + j];
    }
}

extern "C" void kernel_launch(void* const* d_in, const int* in_sizes, int n_in,
                              void* d_out, int out_size, void* d_ws, size_t ws_size,
                              hipStream_t stream) {
    const float* des   = (const float*)d_in[0];
    const float* tweet = (const float*)d_in[1];
    const float* nprop = (const float*)d_in[2];
    const float* cprop = (const float*)d_in[3];
    const int*   eidx  = (const int*)d_in[4];
    // d_in[5] = edge_type (unused by the forward pass)
    const float* Wd = (const float*)d_in[6];  const float* bd = (const float*)d_in[7];
    const float* Wt = (const float*)d_in[8];  const float* bt = (const float*)d_in[9];
    const float* Wn = (const float*)d_in[10]; const float* bn = (const float*)d_in[11];
    const float* Wc = (const float*)d_in[12]; const float* bc = (const float*)d_in[13];
    const float* Wi = (const float*)d_in[14]; const float* bi = (const float*)d_in[15];
    const float* W1 = (const float*)d_in[16]; const float* a1s = (const float*)d_in[17];
    const float* a1d = (const float*)d_in[18]; const float* b1 = (const float*)d_in[19];
    const float* W2 = (const float*)d_in[20]; const float* a2s = (const float*)d_in[21];
    const float* a2d = (const float*)d_in[22]; const float* b2 = (const float*)d_in[23];
    const float* Wg = (const float*)d_in[24];
    const float* We1 = (const float*)d_in[25]; const float* be1 = (const float*)d_in[26];
    const float* We2 = (const float*)d_in[27]; const float* be2 = (const float*)d_in[28];
    float* out = (float*)d_out;

    const int* src = eidx;
    const int* dst = eidx + NE;

    float* bufA = (float*)d_ws;                      // xl2            [N*128]
    float* bufB = bufA + (size_t)NN * 128;           // xl1, then x3   [N*128]
    float* as1  = bufB + (size_t)NN * 128;           // [N*4]
    float* ad1  = as1 + (size_t)NN * 4;              // [N*4]
    float* as2  = ad1 + (size_t)NN * 4;              // [N]
    float* ad2  = as2 + NN;                          // [N]
    int* deg    = (int*)(ad2 + NN);                  // [N]
    int* rowptr = deg + NN;                          // [N+1]
    int* cursor = rowptr + NN + 1;                   // [N]
    int* csr    = cursor + NN;                       // [E]

    hipMemsetAsync(deg, 0, NN * sizeof(int), stream);
    k_enc<<<NN / ENB, 256, 0, stream>>>(des, tweet, nprop, cprop, Wd, bd, Wt, bt, Wn, bn,
                                        Wc, bc, Wi, bi, W1, a1s, a1d, bufB, as1, ad1);
    k_deg<<<(NE + 255) / 256, 256, 0, stream>>>(dst, deg);
    k_scan<<<1, 1024, 0, stream>>>(deg, rowptr, cursor);
    k_fill<<<(NE + 255) / 256, 256, 0, stream>>>(src, dst, cursor, csr);
    k_gat1<<<NN / 4, 256, 0, stream>>>(bufB, as1, ad1, b1, rowptr, csr, W2, a2s, a2d,
                                       bufA, as2, ad2);
    k_gat2<<<NN / 4, 256, 0, stream>>>(bufA, as2, ad2, b2, rowptr, csr, bufB);
    k_moe<<<NN / 16, 256, 0, stream>>>(bufB, Wg, We1, be1, We2, be2, out);
}

// Round 3
// 2172.712 us; speedup vs baseline: 1.2683x; 1.2683x over previous
//
#include <hip/hip_runtime.h>
#include <math.h>

#define NN 100000
#define NE 3200000
#define ENB 32            // nodes per block in encoder (100000 = 32*3125 exactly)
#define KT 64             // K-tile for phase A staging
#define X0S 132           // LDS row stride for x0/x1 (bank-spread for reductions)
#define NB_SCAN 391       // ceil(NN/256)

__device__ __forceinline__ float selu_f(float x) {
    const float a = 1.6732632423543772f;
    const float s = 1.0507009873554805f;
    return x > 0.f ? s * x : s * a * (__expf(x) - 1.f);
}
__device__ __forceinline__ float lrelu02(float x)  { return fmaxf(x, 0.2f * x); }
__device__ __forceinline__ float lrelu001(float x) { return fmaxf(x, 0.01f * x); }

// ---------------- encoder: x0 -> x1 -> xl1 (+att1 sums). x0/x1 never hit HBM ----
// Uniform structure: x rows live in LDS, read as broadcast b128; weights stream
// from L2 with 4 coalesced scalar loads per 4-k step. VMEM:FMA ~ 1:8..1:16.
__global__ __launch_bounds__(256) void k_enc(
    const float* __restrict__ des, const float* __restrict__ tweet,
    const float* __restrict__ nprop, const float* __restrict__ cprop,
    const float* __restrict__ Wd, const float* __restrict__ bd,
    const float* __restrict__ Wt, const float* __restrict__ bt,
    const float* __restrict__ Wn, const float* __restrict__ bn,
    const float* __restrict__ Wc, const float* __restrict__ bc,
    const float* __restrict__ Wi, const float* __restrict__ bi,
    const float* __restrict__ W1, const float* __restrict__ a1s,
    const float* __restrict__ a1d,
    float* __restrict__ xl1, float* __restrict__ as1, float* __restrict__ ad1)
{
    __shared__ float R0[ENB * X0S];   // phase A stage -> x0 -> reduction buffer
    __shared__ float R1[ENB * X0S];   // x1
    const int t = threadIdx.x;
    const int gbase = blockIdx.x * ENB;

    // ---------- phase A: des/tweet long dots (LDS-staged K-tiles) ----------
    {
        float* Ad = R0;               // [ENB][KT] row-major, contiguous
        float* At = R0 + ENB * KT;
        const int c  = t & 63;        // 0..31 des-ch, 32..63 tweet-ch
        const int jg = t >> 6;        // 0..3 -> nodes jg*8..+7
        const float* Wrow = (c < 32) ? (Wd + c) : (Wt + (c - 32));
        float acc[8];
#pragma unroll
        for (int j = 0; j < 8; ++j) acc[j] = 0.f;

        for (int kt0 = 0; kt0 < 768; kt0 += KT) {
            __syncthreads();          // protect stage region from prev-iter readers
#pragma unroll
            for (int r = 0; r < 2; ++r) {
                const int idx = r * 256 + t;          // 0..511
                const int node = idx >> 4;            // 16 float4 per 64-float row
                const int q = idx & 15;
                const size_t g = (size_t)(gbase + node) * 768 + kt0 + q * 4;
                reinterpret_cast<float4*>(Ad)[idx] = *reinterpret_cast<const float4*>(des + g);
                reinterpret_cast<float4*>(At)[idx] = *reinterpret_cast<const float4*>(tweet + g);
            }
            __syncthreads();
            const float* Arow = (c < 32) ? Ad : At;
            for (int k4 = 0; k4 < KT; k4 += 4) {
                const float w0 = Wrow[(kt0 + k4 + 0) * 32];
                const float w1 = Wrow[(kt0 + k4 + 1) * 32];
                const float w2 = Wrow[(kt0 + k4 + 2) * 32];
                const float w3 = Wrow[(kt0 + k4 + 3) * 32];
#pragma unroll
                for (int j = 0; j < 8; ++j) {
                    const float4 av = *reinterpret_cast<const float4*>(&Arow[(jg * 8 + j) * KT + k4]);
                    acc[j] = fmaf(av.x, w0, fmaf(av.y, w1, fmaf(av.z, w2, fmaf(av.w, w3, acc[j]))));
                }
            }
        }
        __syncthreads();              // all reads of stage done; reuse R0 as x0
        const float bv = (c < 32) ? bd[c] : bt[c - 32];
#pragma unroll
        for (int j = 0; j < 8; ++j)
            R0[(jg * 8 + j) * X0S + c] = selu_f(acc[j] + bv);
        // num_prop / cat_prop channels 64..127
        if (c < 32) {
#pragma unroll
            for (int j = 0; j < 8; ++j) {
                const int node = gbase + jg * 8 + j;
                float v = 0.f;
                for (int k = 0; k < 5; ++k) v = fmaf(nprop[node * 5 + k], Wn[k * 32 + c], v);
                R0[(jg * 8 + j) * X0S + 64 + c] = selu_f(v + bn[c]);
            }
        } else {
            const int cc = c - 32;
#pragma unroll
            for (int j = 0; j < 8; ++j) {
                const int node = gbase + jg * 8 + j;
                float v = 0.f;
                for (int k = 0; k < 3; ++k) v = fmaf(cprop[node * 3 + k], Wc[k * 32 + cc], v);
                R0[(jg * 8 + j) * X0S + 96 + cc] = selu_f(v + bc[cc]);
            }
        }
    }
    __syncthreads();

    const int c  = t & 127;
    const int jg = t >> 7;            // 0..1 -> nodes jg*16..+15

    // ---------- phase B: x1 = selu(x0 @ Wi + bi) ----------
    {
        float acc[16];
#pragma unroll
        for (int j = 0; j < 16; ++j) acc[j] = 0.f;
        for (int k4 = 0; k4 < 128; k4 += 4) {
            const float w0 = Wi[(k4 + 0) * 128 + c];
            const float w1 = Wi[(k4 + 1) * 128 + c];
            const float w2 = Wi[(k4 + 2) * 128 + c];
            const float w3 = Wi[(k4 + 3) * 128 + c];
#pragma unroll
            for (int j = 0; j < 16; ++j) {
                const float4 xv = *reinterpret_cast<const float4*>(&R0[(jg * 16 + j) * X0S + k4]);
                acc[j] = fmaf(xv.x, w0, fmaf(xv.y, w1, fmaf(xv.z, w2, fmaf(xv.w, w3, acc[j]))));
            }
        }
        const float bv = bi[c];
#pragma unroll
        for (int j = 0; j < 16; ++j)
            R1[(jg * 16 + j) * X0S + c] = selu_f(acc[j] + bv);
    }
    __syncthreads();

    // ---------- phase C: xl1 = x1 @ W1 (+att1 partial sums) ----------
    {
        float acc[16];
#pragma unroll
        for (int j = 0; j < 16; ++j) acc[j] = 0.f;
        for (int k4 = 0; k4 < 128; k4 += 4) {
            const float w0 = W1[(k4 + 0) * 128 + c];
            const float w1 = W1[(k4 + 1) * 128 + c];
            const float w2 = W1[(k4 + 2) * 128 + c];
            const float w3 = W1[(k4 + 3) * 128 + c];
#pragma unroll
            for (int j = 0; j < 16; ++j) {
                const float4 xv = *reinterpret_cast<const float4*>(&R1[(jg * 16 + j) * X0S + k4]);
                acc[j] = fmaf(xv.x, w0, fmaf(xv.y, w1, fmaf(xv.z, w2, fmaf(xv.w, w3, acc[j]))));
            }
        }
#pragma unroll
        for (int j = 0; j < 16; ++j)
            xl1[(size_t)(gbase + jg * 16 + j) * 128 + c] = acc[j];

        // attention sums: reuse R0 (x0 dead after phase B)
        const float vs = a1s[c];
#pragma unroll
        for (int j = 0; j < 16; ++j) R0[(jg * 16 + j) * X0S + c] = acc[j] * vs;
        __syncthreads();
        if (t < 128) {
            const int node = t >> 2, h = t & 3;
            float4 s4 = make_float4(0.f, 0.f, 0.f, 0.f);
            for (int i = 0; i < 8; ++i) {
                const float4 v = *reinterpret_cast<const float4*>(&R0[node * X0S + h * 32 + i * 4]);
                s4.x += v.x; s4.y += v.y; s4.z += v.z; s4.w += v.w;
            }
            as1[(gbase + node) * 4 + h] = s4.x + s4.y + s4.z + s4.w;
        }
        __syncthreads();
        const float vd = a1d[c];
#pragma unroll
        for (int j = 0; j < 16; ++j) R0[(jg * 16 + j) * X0S + c] = acc[j] * vd;
        __syncthreads();
        if (t < 128) {
            const int node = t >> 2, h = t & 3;
            float4 s4 = make_float4(0.f, 0.f, 0.f, 0.f);
            for (int i = 0; i < 8; ++i) {
                const float4 v = *reinterpret_cast<const float4*>(&R0[node * X0S + h * 32 + i * 4]);
                s4.x += v.x; s4.y += v.y; s4.z += v.z; s4.w += v.w;
            }
            ad1[(gbase + node) * 4 + h] = s4.x + s4.y + s4.z + s4.w;
        }
    }
}

// ---------------- CSR build ----------------
__global__ __launch_bounds__(256) void k_deg(const int* __restrict__ dst, int* __restrict__ deg) {
    const int e = blockIdx.x * 256 + threadIdx.x;
    if (e < NE) atomicAdd(&deg[dst[e]], 1);
}

// hierarchical scan: block sums -> scan sums -> per-block scan
__global__ __launch_bounds__(256) void k_scan1(const int* __restrict__ deg, int* __restrict__ bsum) {
    __shared__ int ws[4];
    const int t = threadIdx.x;
    const int i = blockIdx.x * 256 + t;
    int v = (i < NN) ? deg[i] : 0;
    for (int off = 32; off; off >>= 1) v += __shfl_down(v, off, 64);
    if ((t & 63) == 0) ws[t >> 6] = v;
    __syncthreads();
    if (t == 0) bsum[blockIdx.x] = ws[0] + ws[1] + ws[2] + ws[3];
}

__global__ __launch_bounds__(512) void k_scan2(const int* __restrict__ bsum,
                                               int* __restrict__ boff, int* __restrict__ rowptr) {
    __shared__ int ws[8];
    const int t = threadIdx.x;
    const int v = (t < NB_SCAN) ? bsum[t] : 0;
    int x = v;
    for (int off = 1; off < 64; off <<= 1) {
        const int u = __shfl_up(x, off, 64);
        if ((t & 63) >= off) x += u;
    }
    if ((t & 63) == 63) ws[t >> 6] = x;
    __syncthreads();
    if (t < 8) {
        int y = ws[t];
        for (int off = 1; off < 8; off <<= 1) {
            const int u = __shfl_up(y, off, 64);
            if (t >= off) y += u;
        }
        ws[t] = y;
    }
    __syncthreads();
    const int wb = (t >> 6) ? ws[(t >> 6) - 1] : 0;
    if (t < NB_SCAN) boff[t] = wb + x - v;
    if (t == NB_SCAN - 1) rowptr[NN] = wb + x;
}

__global__ __launch_bounds__(256) void k_scan3(const int* __restrict__ deg, const int* __restrict__ boff,
                                               int* __restrict__ rowptr, int* __restrict__ cursor) {
    __shared__ int ws[4];
    const int t = threadIdx.x;
    const int i = blockIdx.x * 256 + t;
    const int v = (i < NN) ? deg[i] : 0;
    int x = v;
    for (int off = 1; off < 64; off <<= 1) {
        const int u = __shfl_up(x, off, 64);
        if ((t & 63) >= off) x += u;
    }
    if ((t & 63) == 63) ws[t >> 6] = x;
    __syncthreads();
    const int wv = t >> 6;
    int wb = 0;
    for (int w = 0; w < 4; ++w) if (w < wv) wb += ws[w];
    const int excl = boff[blockIdx.x] + wb + x - v;
    if (i < NN) { rowptr[i] = excl; cursor[i] = excl; }
}

__global__ __launch_bounds__(256) void k_fill(const int* __restrict__ src, const int* __restrict__ dst,
                                              int* __restrict__ cursor, int* __restrict__ csr) {
    const int e = blockIdx.x * 256 + threadIdx.x;
    if (e < NE) {
        const int pos = atomicAdd(&cursor[dst[e]], 1);
        csr[pos] = src[e];
    }
}

// ---------------- GAT1 aggregate (4 heads, online softmax) + fused xl2 = x2@W2 ----
__global__ __launch_bounds__(256) void k_gat1(
    const float* __restrict__ xl, const float* __restrict__ as_,
    const float* __restrict__ ad_, const float* __restrict__ b1,
    const int* __restrict__ rowptr, const int* __restrict__ csr,
    const float* __restrict__ W2, const float* __restrict__ a2s, const float* __restrict__ a2d,
    float* __restrict__ xl2, float* __restrict__ as2, float* __restrict__ ad2)
{
    __shared__ float xs[4][128];
    __shared__ float ps[4][128], pd[4][128];
    const int t = threadIdx.x;
    const int wv = t >> 6, lane = t & 63;
    const int d = blockIdx.x * 4 + wv;
    const int c0 = lane * 2;
    const int h = c0 >> 5;                      // head of both my channels

    const float adv = ad_[d * 4 + h];
    const float a_self = lrelu02(as_[d * 4 + h] + adv);
    const int beg = rowptr[d], end = rowptr[d + 1];

    float m = a_self, z = 1.f;
    const float2 xv = *reinterpret_cast<const float2*>(xl + (size_t)d * 128 + c0);
    float acc0 = xv.x, acc1 = xv.y;
#pragma unroll 2
    for (int i = beg; i < end; ++i) {
        const int s = csr[i];
        const float a = lrelu02(as_[s * 4 + h] + adv);
        const float mn = fmaxf(m, a);
        const float sc = __expf(m - mn);
        const float e  = __expf(a - mn);
        const float2 v = *reinterpret_cast<const float2*>(xl + (size_t)s * 128 + c0);
        z    = fmaf(z, sc, e);
        acc0 = fmaf(acc0, sc, e * v.x);
        acc1 = fmaf(acc1, sc, e * v.y);
        m = mn;
    }
    const float inv = 1.f / z;
    xs[wv][c0]     = acc0 * inv + b1[c0];
    xs[wv][c0 + 1] = acc1 * inv + b1[c0 + 1];
    __syncthreads();

    const int base = blockIdx.x * 4;
    for (int p = 0; p < 2; ++p) {
        const int idx = p * 256 + t;
        const int n = idx >> 7, cc = idx & 127;
        float acc = 0.f;
        for (int k = 0; k < 128; k += 4) {
            acc = fmaf(xs[n][k + 0], W2[(k + 0) * 128 + cc], acc);
            acc = fmaf(xs[n][k + 1], W2[(k + 1) * 128 + cc], acc);
            acc = fmaf(xs[n][k + 2], W2[(k + 2) * 128 + cc], acc);
            acc = fmaf(xs[n][k + 3], W2[(k + 3) * 128 + cc], acc);
        }
        xl2[(size_t)(base + n) * 128 + cc] = acc;
        ps[n][cc] = acc * a2s[cc];
        pd[n][cc] = acc * a2d[cc];
    }
    __syncthreads();
    if (t < 8) {
        const int n = t >> 1, w = t & 1;
        const float* pp = w ? pd[n] : ps[n];
        float sum = 0.f;
        for (int j = 0; j < 128; ++j) sum += pp[j];
        if (w) ad2[base + n] = sum; else as2[base + n] = sum;
    }
}

// ---------------- GAT2 aggregate (1 head, online softmax) -> x3 ----------------
__global__ __launch_bounds__(256) void k_gat2(
    const float* __restrict__ xl, const float* __restrict__ as_,
    const float* __restrict__ ad_, const float* __restrict__ b2,
    const int* __restrict__ rowptr, const int* __restrict__ csr,
    float* __restrict__ x3)
{
    const int t = threadIdx.x;
    const int wv = t >> 6, lane = t & 63;
    const int d = blockIdx.x * 4 + wv;
    const int c0 = lane * 2;

    const float adv = ad_[d];
    const float a_self = lrelu02(as_[d] + adv);
    const int beg = rowptr[d], end = rowptr[d + 1];

    float m = a_self, z = 1.f;
    const float2 xv = *reinterpret_cast<const float2*>(xl + (size_t)d * 128 + c0);
    float acc0 = xv.x, acc1 = xv.y;
#pragma unroll 2
    for (int i = beg; i < end; ++i) {
        const int s = csr[i];
        const float a = lrelu02(as_[s] + adv);
        const float mn = fmaxf(m, a);
        const float sc = __expf(m - mn);
        const float e  = __expf(a - mn);
        const float2 v = *reinterpret_cast<const float2*>(xl + (size_t)s * 128 + c0);
        z    = fmaf(z, sc, e);
        acc0 = fmaf(acc0, sc, e * v.x);
        acc1 = fmaf(acc1, sc, e * v.y);
        m = mn;
    }
    const float inv = 1.f / z;
    float2 o;
    o.x = acc0 * inv + b2[c0];
    o.y = acc1 * inv + b2[c0 + 1];
    *reinterpret_cast<float2*>(x3 + (size_t)d * 128 + c0) = o;
}

// ---------------- MoE: top-1 gate == argmax; expert MLP ----------------
__global__ __launch_bounds__(256) void k_moe(
    const float* __restrict__ x, const float* __restrict__ Wg,
    const float* __restrict__ We1, const float* __restrict__ be1,
    const float* __restrict__ We2, const float* __restrict__ be2,
    float* __restrict__ out)
{
    __shared__ float xs[16][128];
    __shared__ float hs[16][128];
    __shared__ int sel[16];
    const int t = threadIdx.x;
    const int base = blockIdx.x * 16;

    for (int i = t; i < 16 * 128; i += 256) {
        const int n = i >> 7, cc = i & 127;
        xs[n][cc] = x[(size_t)(base + n) * 128 + cc];
    }
    __syncthreads();
    if (t < 16) {
        float g0 = 0.f, g1 = 0.f;
        for (int k = 0; k < 128; ++k) {
            g0 = fmaf(xs[t][k], Wg[k * 2 + 0], g0);
            g1 = fmaf(xs[t][k], Wg[k * 2 + 1], g1);
        }
        sel[t] = (g1 > g0) ? 1 : 0;
    }
    __syncthreads();

    const int half = t >> 7, cc = t & 127;
    const int n0 = half * 8;
    float acc[8];
#pragma unroll
    for (int i = 0; i < 8; ++i) acc[i] = 0.f;
    for (int k = 0; k < 128; ++k) {
        const float w0 = We1[k * 128 + cc];
        const float w1 = We1[128 * 128 + k * 128 + cc];
#pragma unroll
        for (int i = 0; i < 8; ++i) {
            const float w = sel[n0 + i] ? w1 : w0;
            acc[i] = fmaf(xs[n0 + i][k], w, acc[i]);
        }
    }
#pragma unroll
    for (int i = 0; i < 8; ++i) {
        const int e = sel[n0 + i];
        hs[n0 + i][cc] = lrelu001(acc[i] + be1[e * 128 + cc]);
    }
    __syncthreads();
    if (t < 32) {
        const int n = t >> 1, j = t & 1;
        const int e = sel[n];
        float o = 0.f;
        for (int k = 0; k < 128; ++k) o = fmaf(hs[n][k], We2[e * 256 + k * 2 + j], o);
        out[(size_t)(base + n) * 2 + j] = o + be2[e * 2 + j];
    }
}

extern "C" void kernel_launch(void* const* d_in, const int* in_sizes, int n_in,
                              void* d_out, int out_size, void* d_ws, size_t ws_size,
                              hipStream_t stream) {
    const float* des   = (const float*)d_in[0];
    const float* tweet = (const float*)d_in[1];
    const float* nprop = (const float*)d_in[2];
    const float* cprop = (const float*)d_in[3];
    const int*   eidx  = (const int*)d_in[4];
    const float* Wd = (const float*)d_in[6];  const float* bd = (const float*)d_in[7];
    const float* Wt = (const float*)d_in[8];  const float* bt = (const float*)d_in[9];
    const float* Wn = (const float*)d_in[10]; const float* bn = (const float*)d_in[11];
    const float* Wc = (const float*)d_in[12]; const float* bc = (const float*)d_in[13];
    const float* Wi = (const float*)d_in[14]; const float* bi = (const float*)d_in[15];
    const float* W1 = (const float*)d_in[16]; const float* a1s = (const float*)d_in[17];
    const float* a1d = (const float*)d_in[18]; const float* b1 = (const float*)d_in[19];
    const float* W2 = (const float*)d_in[20]; const float* a2s = (const float*)d_in[21];
    const float* a2d = (const float*)d_in[22]; const float* b2 = (const float*)d_in[23];
    const float* Wg = (const float*)d_in[24];
    const float* We1 = (const float*)d_in[25]; const float* be1 = (const float*)d_in[26];
    const float* We2 = (const float*)d_in[27]; const float* be2 = (const float*)d_in[28];
    float* out = (float*)d_out;

    const int* src = eidx;
    const int* dst = eidx + NE;

    float* bufA = (float*)d_ws;                      // xl2            [N*128]
    float* bufB = bufA + (size_t)NN * 128;           // xl1, then x3   [N*128]
    float* as1  = bufB + (size_t)NN * 128;           // [N*4]
    float* ad1  = as1 + (size_t)NN * 4;              // [N*4]
    float* as2  = ad1 + (size_t)NN * 4;              // [N]
    float* ad2  = as2 + NN;                          // [N]
    int* deg    = (int*)(ad2 + NN);                  // [N]
    int* rowptr = deg + NN;                          // [N+1]
    int* cursor = rowptr + NN + 1;                   // [N]
    int* csr    = cursor + NN;                       // [E]
    int* bsum   = csr + NE;                          // [NB_SCAN]
    int* boff   = bsum + NB_SCAN;                    // [NB_SCAN]

    hipMemsetAsync(deg, 0, NN * sizeof(int), stream);
    k_enc<<<NN / ENB, 256, 0, stream>>>(des, tweet, nprop, cprop, Wd, bd, Wt, bt, Wn, bn,
                                        Wc, bc, Wi, bi, W1, a1s, a1d, bufB, as1, ad1);
    k_deg<<<(NE + 255) / 256, 256, 0, stream>>>(dst, deg);
    k_scan1<<<NB_SCAN, 256, 0, stream>>>(deg, bsum);
    k_scan2<<<1, 512, 0, stream>>>(bsum, boff, rowptr);
    k_scan3<<<NB_SCAN, 256, 0, stream>>>(deg, boff, rowptr, cursor);
    k_fill<<<(NE + 255) / 256, 256, 0, stream>>>(src, dst, cursor, csr);
    k_gat1<<<NN / 4, 256, 0, stream>>>(bufB, as1, ad1, b1, rowptr, csr, W2, a2s, a2d,
                                       bufA, as2, ad2);
    k_gat2<<<NN / 4, 256, 0, stream>>>(bufA, as2, ad2, b2, rowptr, csr, bufB);
    k_moe<<<NN / 16, 256, 0, stream>>>(bufB, Wg, We1, be1, We2, be2, out);
}

// Round 5
// 2034.461 us; speedup vs baseline: 1.3545x; 1.0680x over previous
//
#include <hip/hip_runtime.h>
#include <math.h>

#define NN 100000
#define NE 3200000
#define ENB 32            // nodes per block in encoder
#define KT 64             // K-tile for phase A staging
#define SROW 68           // stage row stride (floats), pad vs 64 to spread banks
#define X0S 136           // x0/x1 LDS row stride; 32*136 == 64*68 exactly
#define NB_SCAN 391       // ceil(NN/256)
#define GP 8              // GAT prefetch batch

__device__ __forceinline__ float selu_f(float x) {
    const float a = 1.6732632423543772f;
    const float s = 1.0507009873554805f;
    return x > 0.f ? s * x : s * a * (__expf(x) - 1.f);
}
__device__ __forceinline__ float lrelu02(float x)  { return fmaxf(x, 0.2f * x); }
__device__ __forceinline__ float lrelu001(float x) { return fmaxf(x, 0.01f * x); }

// ---------------- encoder: x0 -> x1 -> xl1 (+att1 sums) ----------------
__global__ __launch_bounds__(256) void k_enc(
    const float* __restrict__ des, const float* __restrict__ tweet,
    const float* __restrict__ nprop, const float* __restrict__ cprop,
    const float* __restrict__ Wd, const float* __restrict__ bd,
    const float* __restrict__ Wt, const float* __restrict__ bt,
    const float* __restrict__ Wn, const float* __restrict__ bn,
    const float* __restrict__ Wc, const float* __restrict__ bc,
    const float* __restrict__ Wi, const float* __restrict__ bi,
    const float* __restrict__ W1, const float* __restrict__ a1s,
    const float* __restrict__ a1d,
    float* __restrict__ xl1, float* __restrict__ as1, float* __restrict__ ad1)
{
    __shared__ float R0[ENB * X0S];   // stage [64][SROW] -> x0 [ENB][X0S]
    __shared__ float R1[ENB * X0S];   // x1
    const int t = threadIdx.x;
    const int gbase = blockIdx.x * ENB;

    // ---------- phase A: des/tweet long dots; 2 ch x 4 nodes per thread ----------
    {
        const int jg  = t >> 5;            // node group (4 nodes), wave-aligned halves
        const int mm  = t & 31;
        const int mat = mm >> 4;           // 0=des, 1=tweet
        const int ch  = mm & 15;           // channels ch, ch+16
        const float* __restrict__ Wp = (mat ? Wt : Wd) + ch;
        const int srow = mat * 32 + jg * 4;

        float acc[2][4];
#pragma unroll
        for (int j = 0; j < 4; ++j) { acc[0][j] = 0.f; acc[1][j] = 0.f; }

        for (int kt0 = 0; kt0 < 768; kt0 += KT) {
            __syncthreads();
            // stage 64 rows x 64 floats (des rows 0..31, tweet rows 32..63)
#pragma unroll
            for (int r = 0; r < 4; ++r) {
                const int idx = r * 256 + t;          // 0..1023
                const int row = idx >> 4;
                const int q = idx & 15;
                const float* bp = (row < 32) ? des : tweet;
                const int nrow = (row < 32) ? row : row - 32;
                const float4 v = *reinterpret_cast<const float4*>(
                    bp + (size_t)(gbase + nrow) * 768 + kt0 + q * 4);
                *reinterpret_cast<float4*>(&R0[row * SROW + q * 4]) = v;
            }
            __syncthreads();
            for (int k4 = 0; k4 < KT; k4 += 4) {
                const float wl0 = Wp[(kt0 + k4 + 0) * 32];
                const float wl1 = Wp[(kt0 + k4 + 1) * 32];
                const float wl2 = Wp[(kt0 + k4 + 2) * 32];
                const float wl3 = Wp[(kt0 + k4 + 3) * 32];
                const float wh0 = Wp[(kt0 + k4 + 0) * 32 + 16];
                const float wh1 = Wp[(kt0 + k4 + 1) * 32 + 16];
                const float wh2 = Wp[(kt0 + k4 + 2) * 32 + 16];
                const float wh3 = Wp[(kt0 + k4 + 3) * 32 + 16];
#pragma unroll
                for (int j = 0; j < 4; ++j) {
                    const float4 av = *reinterpret_cast<const float4*>(&R0[(srow + j) * SROW + k4]);
                    acc[0][j] = fmaf(av.x, wl0, fmaf(av.y, wl1, fmaf(av.z, wl2, fmaf(av.w, wl3, acc[0][j]))));
                    acc[1][j] = fmaf(av.x, wh0, fmaf(av.y, wh1, fmaf(av.z, wh2, fmaf(av.w, wh3, acc[1][j]))));
                }
            }
        }
        __syncthreads();              // stage reads done; R0 becomes x0
        const float blo = mat ? bt[ch] : bd[ch];
        const float bhi = mat ? bt[ch + 16] : bd[ch + 16];
#pragma unroll
        for (int j = 0; j < 4; ++j) {
            const int node = jg * 4 + j;
            R0[node * X0S + mat * 32 + ch]      = selu_f(acc[0][j] + blo);
            R0[node * X0S + mat * 32 + ch + 16] = selu_f(acc[1][j] + bhi);
        }
        // num_prop / cat_prop channels 64..127
        const int ch64 = t & 63;
        const int ng = t >> 6;
        if (ch64 < 32) {
            const float bv = bn[ch64];
#pragma unroll
            for (int j = 0; j < 8; ++j) {
                const int node = ng * 8 + j;
                const float* r = nprop + (size_t)(gbase + node) * 5;
                float v = 0.f;
                for (int k = 0; k < 5; ++k) v = fmaf(r[k], Wn[k * 32 + ch64], v);
                R0[node * X0S + 64 + ch64] = selu_f(v + bv);
            }
        } else {
            const int cc = ch64 - 32;
            const float bv = bc[cc];
#pragma unroll
            for (int j = 0; j < 8; ++j) {
                const int node = ng * 8 + j;
                const float* r = cprop + (size_t)(gbase + node) * 3;
                float v = 0.f;
                for (int k = 0; k < 3; ++k) v = fmaf(r[k], Wc[k * 32 + cc], v);
                R0[node * X0S + 96 + cc] = selu_f(v + bv);
            }
        }
    }
    __syncthreads();

    const int c  = t & 63;             // channels c, c+64
    const int g2 = t >> 6;             // 8 nodes, wave-aligned

    // ---------- phase B: x1 = selu(x0 @ Wi + bi) ----------
    {
        float acc[2][8];
#pragma unroll
        for (int j = 0; j < 8; ++j) { acc[0][j] = 0.f; acc[1][j] = 0.f; }
        for (int k4 = 0; k4 < 128; k4 += 4) {
            const float wl0 = Wi[(k4 + 0) * 128 + c];
            const float wl1 = Wi[(k4 + 1) * 128 + c];
            const float wl2 = Wi[(k4 + 2) * 128 + c];
            const float wl3 = Wi[(k4 + 3) * 128 + c];
            const float wh0 = Wi[(k4 + 0) * 128 + c + 64];
            const float wh1 = Wi[(k4 + 1) * 128 + c + 64];
            const float wh2 = Wi[(k4 + 2) * 128 + c + 64];
            const float wh3 = Wi[(k4 + 3) * 128 + c + 64];
#pragma unroll
            for (int j = 0; j < 8; ++j) {
                const float4 xv = *reinterpret_cast<const float4*>(&R0[(g2 * 8 + j) * X0S + k4]);
                acc[0][j] = fmaf(xv.x, wl0, fmaf(xv.y, wl1, fmaf(xv.z, wl2, fmaf(xv.w, wl3, acc[0][j]))));
                acc[1][j] = fmaf(xv.x, wh0, fmaf(xv.y, wh1, fmaf(xv.z, wh2, fmaf(xv.w, wh3, acc[1][j]))));
            }
        }
        const float blo = bi[c], bhi = bi[c + 64];
#pragma unroll
        for (int j = 0; j < 8; ++j) {
            R1[(g2 * 8 + j) * X0S + c]      = selu_f(acc[0][j] + blo);
            R1[(g2 * 8 + j) * X0S + c + 64] = selu_f(acc[1][j] + bhi);
        }
    }
    __syncthreads();

    // ---------- phase C: xl1 = x1 @ W1 (+att1 sums via shuffles) ----------
    {
        float acc[2][8];
#pragma unroll
        for (int j = 0; j < 8; ++j) { acc[0][j] = 0.f; acc[1][j] = 0.f; }
        for (int k4 = 0; k4 < 128; k4 += 4) {
            const float wl0 = W1[(k4 + 0) * 128 + c];
            const float wl1 = W1[(k4 + 1) * 128 + c];
            const float wl2 = W1[(k4 + 2) * 128 + c];
            const float wl3 = W1[(k4 + 3) * 128 + c];
            const float wh0 = W1[(k4 + 0) * 128 + c + 64];
            const float wh1 = W1[(k4 + 1) * 128 + c + 64];
            const float wh2 = W1[(k4 + 2) * 128 + c + 64];
            const float wh3 = W1[(k4 + 3) * 128 + c + 64];
#pragma unroll
            for (int j = 0; j < 8; ++j) {
                const float4 xv = *reinterpret_cast<const float4*>(&R1[(g2 * 8 + j) * X0S + k4]);
                acc[0][j] = fmaf(xv.x, wl0, fmaf(xv.y, wl1, fmaf(xv.z, wl2, fmaf(xv.w, wl3, acc[0][j]))));
                acc[1][j] = fmaf(xv.x, wh0, fmaf(xv.y, wh1, fmaf(xv.z, wh2, fmaf(xv.w, wh3, acc[1][j]))));
            }
        }
        const float slo = a1s[c], shi = a1s[c + 64];
        const float dlo = a1d[c], dhi = a1d[c + 64];
#pragma unroll
        for (int j = 0; j < 8; ++j) {
            const size_t node = (size_t)gbase + g2 * 8 + j;
            xl1[node * 128 + c]      = acc[0][j];
            xl1[node * 128 + c + 64] = acc[1][j];
            float v0 = acc[0][j] * slo;   // head c>>5
            float v1 = acc[1][j] * shi;   // head 2+(c>>5)
            float v2 = acc[0][j] * dlo;
            float v3 = acc[1][j] * dhi;
#pragma unroll
            for (int off = 16; off; off >>= 1) {
                v0 += __shfl_xor(v0, off, 32);
                v1 += __shfl_xor(v1, off, 32);
                v2 += __shfl_xor(v2, off, 32);
                v3 += __shfl_xor(v3, off, 32);
            }
            if ((c & 31) == 0) {
                const int hh = c >> 5;
                as1[node * 4 + hh]     = v0;
                as1[node * 4 + 2 + hh] = v1;
                ad1[node * 4 + hh]     = v2;
                ad1[node * 4 + 2 + hh] = v3;
            }
        }
    }
}

// ---------------- CSR build ----------------
__global__ __launch_bounds__(256) void k_deg(const int* __restrict__ dst, int* __restrict__ deg) {
    const int e = blockIdx.x * 256 + threadIdx.x;
    if (e < NE) atomicAdd(&deg[dst[e]], 1);
}

__global__ __launch_bounds__(256) void k_scan1(const int* __restrict__ deg, int* __restrict__ bsum) {
    __shared__ int ws[4];
    const int t = threadIdx.x;
    const int i = blockIdx.x * 256 + t;
    int v = (i < NN) ? deg[i] : 0;
    for (int off = 32; off; off >>= 1) v += __shfl_down(v, off, 64);
    if ((t & 63) == 0) ws[t >> 6] = v;
    __syncthreads();
    if (t == 0) bsum[blockIdx.x] = ws[0] + ws[1] + ws[2] + ws[3];
}

__global__ __launch_bounds__(512) void k_scan2(const int* __restrict__ bsum,
                                               int* __restrict__ boff, int* __restrict__ rowptr) {
    __shared__ int ws[8];
    const int t = threadIdx.x;
    const int v = (t < NB_SCAN) ? bsum[t] : 0;
    int x = v;
    for (int off = 1; off < 64; off <<= 1) {
        const int u = __shfl_up(x, off, 64);
        if ((t & 63) >= off) x += u;
    }
    if ((t & 63) == 63) ws[t >> 6] = x;
    __syncthreads();
    if (t < 8) {
        int y = ws[t];
        for (int off = 1; off < 8; off <<= 1) {
            const int u = __shfl_up(y, off, 64);
            if (t >= off) y += u;
        }
        ws[t] = y;
    }
    __syncthreads();
    const int wb = (t >> 6) ? ws[(t >> 6) - 1] : 0;
    if (t < NB_SCAN) boff[t] = wb + x - v;
    if (t == NB_SCAN - 1) rowptr[NN] = wb + x;
}

__global__ __launch_bounds__(256) void k_scan3(const int* __restrict__ deg, const int* __restrict__ boff,
                                               int* __restrict__ rowptr, int* __restrict__ cursor) {
    __shared__ int ws[4];
    const int t = threadIdx.x;
    const int i = blockIdx.x * 256 + t;
    const int v = (i < NN) ? deg[i] : 0;
    int x = v;
    for (int off = 1; off < 64; off <<= 1) {
        const int u = __shfl_up(x, off, 64);
        if ((t & 63) >= off) x += u;
    }
    if ((t & 63) == 63) ws[t >> 6] = x;
    __syncthreads();
    const int wv = t >> 6;
    int wb = 0;
    for (int w = 0; w < 4; ++w) if (w < wv) wb += ws[w];
    const int excl = boff[blockIdx.x] + wb + x - v;
    if (i < NN) { rowptr[i] = excl; cursor[i] = excl; }
}

__global__ __launch_bounds__(256) void k_fill(const int* __restrict__ src, const int* __restrict__ dst,
                                              int* __restrict__ cursor, int* __restrict__ csr) {
    const int e = blockIdx.x * 256 + threadIdx.x;
    if (e < NE) {
        const int pos = atomicAdd(&cursor[dst[e]], 1);
        csr[pos] = src[e];
    }
}

// ---------------- GAT1: 4 heads, online softmax, 8-edge pipelined prefetch ----
__global__ __launch_bounds__(256) void k_gat1(
    const float* __restrict__ xl, const float* __restrict__ as_,
    const float* __restrict__ ad_, const float* __restrict__ b1,
    const int* __restrict__ rowptr, const int* __restrict__ csr,
    const float* __restrict__ W2, const float* __restrict__ a2s, const float* __restrict__ a2d,
    float* __restrict__ xl2, float* __restrict__ as2, float* __restrict__ ad2)
{
    __shared__ float xs[4][128];
    __shared__ float ps[4][128], pd[4][128];
    const int t = threadIdx.x;
    const int wv = t >> 6, lane = t & 63;
    const int d = blockIdx.x * 4 + wv;
    const int c0 = lane * 2;
    const int h = c0 >> 5;

    const float adv = ad_[(size_t)d * 4 + h];
    const float a_self = lrelu02(as_[(size_t)d * 4 + h] + adv);
    const int beg = rowptr[d], end = rowptr[d + 1];
    const int nb = (end - beg + GP - 1) / GP;

    float m = a_self, z = 1.f;
    const float2 xv = *reinterpret_cast<const float2*>(xl + (size_t)d * 128 + c0);
    float acc0 = xv.x, acc1 = xv.y;

    int sA[GP], sB[GP];
    float aA[GP], aB[GP];
    float2 vA[GP], vB[GP];

    auto CSRL = [&](int b, int (&sb)[GP]) {
#pragma unroll
        for (int j = 0; j < GP; ++j) {
            const int idx = beg + b * GP + j;
            sb[j] = (idx < end) ? csr[idx] : -1;
        }
    };
    auto GATH = [&](const int (&sb)[GP], float (&ab)[GP], float2 (&vb)[GP]) {
#pragma unroll
        for (int j = 0; j < GP; ++j) {
            const int s = sb[j];
            const int sa = (s < 0) ? d : s;
            const float av = as_[(size_t)sa * 4 + h];
            ab[j] = (s < 0) ? -INFINITY : av;
            vb[j] = *reinterpret_cast<const float2*>(xl + (size_t)sa * 128 + c0);
        }
    };
    auto PROC = [&](const float (&ab)[GP], const float2 (&vb)[GP]) {
#pragma unroll
        for (int j = 0; j < GP; ++j) {
            const float a = lrelu02(ab[j] + adv);
            const float mn = fmaxf(m, a);
            const float sc = __expf(m - mn);
            const float e  = __expf(a - mn);
            z    = fmaf(z, sc, e);
            acc0 = fmaf(acc0, sc, e * vb[j].x);
            acc1 = fmaf(acc1, sc, e * vb[j].y);
            m = mn;
        }
    };

    if (nb > 0) {
        CSRL(0, sA);
        if (nb > 1) CSRL(1, sB);
        GATH(sA, aA, vA);
        int b = 0;
        while (true) {
            if (b + 1 < nb) GATH(sB, aB, vB);
            if (b + 2 < nb) CSRL(b + 2, sA);
            PROC(aA, vA);
            if (++b >= nb) break;
            if (b + 1 < nb) GATH(sA, aA, vA);
            if (b + 2 < nb) CSRL(b + 2, sB);
            PROC(aB, vB);
            if (++b >= nb) break;
        }
    }
    const float inv = 1.f / z;
    xs[wv][c0]     = fmaf(acc0, inv, b1[c0]);
    xs[wv][c0 + 1] = fmaf(acc1, inv, b1[c0 + 1]);
    __syncthreads();

    // fused xl2 = x2 @ W2 (+att2 products); thread -> (cc, 2 nodes)
    const int base = blockIdx.x * 4;
    const int cc = t & 127;
    const int np = (t >> 7) * 2;
    {
        float g0 = 0.f, g1 = 0.f;
        for (int k4 = 0; k4 < 128; k4 += 4) {
            const float w0 = W2[(k4 + 0) * 128 + cc];
            const float w1 = W2[(k4 + 1) * 128 + cc];
            const float w2 = W2[(k4 + 2) * 128 + cc];
            const float w3 = W2[(k4 + 3) * 128 + cc];
            const float4 x0v = *reinterpret_cast<const float4*>(&xs[np][k4]);
            const float4 x1v = *reinterpret_cast<const float4*>(&xs[np + 1][k4]);
            g0 = fmaf(x0v.x, w0, fmaf(x0v.y, w1, fmaf(x0v.z, w2, fmaf(x0v.w, w3, g0))));
            g1 = fmaf(x1v.x, w0, fmaf(x1v.y, w1, fmaf(x1v.z, w2, fmaf(x1v.w, w3, g1))));
        }
        xl2[(size_t)(base + np) * 128 + cc]     = g0;
        xl2[(size_t)(base + np + 1) * 128 + cc] = g1;
        const float s2 = a2s[cc], d2 = a2d[cc];
        ps[np][cc] = g0 * s2;     pd[np][cc] = g0 * d2;
        ps[np + 1][cc] = g1 * s2; pd[np + 1][cc] = g1 * d2;
    }
    __syncthreads();
    {
        const int tn = t & 127;
        const int node = tn >> 5, q = tn & 31;
        const float* pp = (t < 128) ? ps[node] : pd[node];
        float v = pp[q] + pp[q + 32] + pp[q + 64] + pp[q + 96];
#pragma unroll
        for (int off = 16; off; off >>= 1) v += __shfl_xor(v, off, 32);
        if (q == 0) {
            if (t < 128) as2[base + node] = v; else ad2[base + node] = v;
        }
    }
}

// ---------------- GAT2: 1 head, online softmax, pipelined -> x3 ----------------
__global__ __launch_bounds__(256) void k_gat2(
    const float* __restrict__ xl, const float* __restrict__ as_,
    const float* __restrict__ ad_, const float* __restrict__ b2,
    const int* __restrict__ rowptr, const int* __restrict__ csr,
    float* __restrict__ x3)
{
    const int t = threadIdx.x;
    const int wv = t >> 6, lane = t & 63;
    const int d = blockIdx.x * 4 + wv;
    const int c0 = lane * 2;

    const float adv = ad_[d];
    const float a_self = lrelu02(as_[d] + adv);
    const int beg = rowptr[d], end = rowptr[d + 1];
    const int nb = (end - beg + GP - 1) / GP;

    float m = a_self, z = 1.f;
    const float2 xv = *reinterpret_cast<const float2*>(xl + (size_t)d * 128 + c0);
    float acc0 = xv.x, acc1 = xv.y;

    int sA[GP], sB[GP];
    float aA[GP], aB[GP];
    float2 vA[GP], vB[GP];

    auto CSRL = [&](int b, int (&sb)[GP]) {
#pragma unroll
        for (int j = 0; j < GP; ++j) {
            const int idx = beg + b * GP + j;
            sb[j] = (idx < end) ? csr[idx] : -1;
        }
    };
    auto GATH = [&](const int (&sb)[GP], float (&ab)[GP], float2 (&vb)[GP]) {
#pragma unroll
        for (int j = 0; j < GP; ++j) {
            const int s = sb[j];
            const int sa = (s < 0) ? d : s;
            const float av = as_[sa];
            ab[j] = (s < 0) ? -INFINITY : av;
            vb[j] = *reinterpret_cast<const float2*>(xl + (size_t)sa * 128 + c0);
        }
    };
    auto PROC = [&](const float (&ab)[GP], const float2 (&vb)[GP]) {
#pragma unroll
        for (int j = 0; j < GP; ++j) {
            const float a = lrelu02(ab[j] + adv);
            const float mn = fmaxf(m, a);
            const float sc = __expf(m - mn);
            const float e  = __expf(a - mn);
            z    = fmaf(z, sc, e);
            acc0 = fmaf(acc0, sc, e * vb[j].x);
            acc1 = fmaf(acc1, sc, e * vb[j].y);
            m = mn;
        }
    };

    if (nb > 0) {
        CSRL(0, sA);
        if (nb > 1) CSRL(1, sB);
        GATH(sA, aA, vA);
        int b = 0;
        while (true) {
            if (b + 1 < nb) GATH(sB, aB, vB);
            if (b + 2 < nb) CSRL(b + 2, sA);
            PROC(aA, vA);
            if (++b >= nb) break;
            if (b + 1 < nb) GATH(sA, aA, vA);
            if (b + 2 < nb) CSRL(b + 2, sB);
            PROC(aB, vB);
            if (++b >= nb) break;
        }
    }
    const float inv = 1.f / z;
    float2 o;
    o.x = fmaf(acc0, inv, b2[c0]);
    o.y = fmaf(acc1, inv, b2[c0 + 1]);
    *reinterpret_cast<float2*>(x3 + (size_t)d * 128 + c0) = o;
}

// ---------------- MoE: top-1 gate == argmax; expert MLP ----------------
__global__ __launch_bounds__(256) void k_moe(
    const float* __restrict__ x, const float* __restrict__ Wg,
    const float* __restrict__ We1, const float* __restrict__ be1,
    const float* __restrict__ We2, const float* __restrict__ be2,
    float* __restrict__ out)
{
    __shared__ float xs[16][128];
    __shared__ float hs[16][128];
    __shared__ int sel[16];
    const int t = threadIdx.x;
    const int base = blockIdx.x * 16;

    for (int i = t; i < 16 * 128; i += 256) {
        const int n = i >> 7, cc = i & 127;
        xs[n][cc] = x[(size_t)(base + n) * 128 + cc];
    }
    __syncthreads();
    if (t < 16) {
        float g0 = 0.f, g1 = 0.f;
        for (int k = 0; k < 128; ++k) {
            g0 = fmaf(xs[t][k], Wg[k * 2 + 0], g0);
            g1 = fmaf(xs[t][k], Wg[k * 2 + 1], g1);
        }
        sel[t] = (g1 > g0) ? 1 : 0;
    }
    __syncthreads();

    const int half = t >> 7, cc = t & 127;
    const int n0 = half * 8;
    float acc[8];
#pragma unroll
    for (int i = 0; i < 8; ++i) acc[i] = 0.f;
    for (int k = 0; k < 128; ++k) {
        const float w0 = We1[k * 128 + cc];
        const float w1 = We1[128 * 128 + k * 128 + cc];
#pragma unroll
        for (int i = 0; i < 8; ++i) {
            const float w = sel[n0 + i] ? w1 : w0;
            acc[i] = fmaf(xs[n0 + i][k], w, acc[i]);
        }
    }
#pragma unroll
    for (int i = 0; i < 8; ++i) {
        const int e = sel[n0 + i];
        hs[n0 + i][cc] = lrelu001(acc[i] + be1[e * 128 + cc]);
    }
    __syncthreads();
    if (t < 32) {
        const int n = t >> 1, j = t & 1;
        const int e = sel[n];
        float o = 0.f;
        for (int k = 0; k < 128; ++k) o = fmaf(hs[n][k], We2[e * 256 + k * 2 + j], o);
        out[(size_t)(base + n) * 2 + j] = o + be2[e * 2 + j];
    }
}

extern "C" void kernel_launch(void* const* d_in, const int* in_sizes, int n_in,
                              void* d_out, int out_size, void* d_ws, size_t ws_size,
                              hipStream_t stream) {
    const float* des   = (const float*)d_in[0];
    const float* tweet = (const float*)d_in[1];
    const float* nprop = (const float*)d_in[2];
    const float* cprop = (const float*)d_in[3];
    const int*   eidx  = (const int*)d_in[4];
    const float* Wd = (const float*)d_in[6];  const float* bd = (const float*)d_in[7];
    const float* Wt = (const float*)d_in[8];  const float* bt = (const float*)d_in[9];
    const float* Wn = (const float*)d_in[10]; const float* bn = (const float*)d_in[11];
    const float* Wc = (const float*)d_in[12]; const float* bc = (const float*)d_in[13];
    const float* Wi = (const float*)d_in[14]; const float* bi = (const float*)d_in[15];
    const float* W1 = (const float*)d_in[16]; const float* a1s = (const float*)d_in[17];
    const float* a1d = (const float*)d_in[18]; const float* b1 = (const float*)d_in[19];
    const float* W2 = (const float*)d_in[20]; const float* a2s = (const float*)d_in[21];
    const float* a2d = (const float*)d_in[22]; const float* b2 = (const float*)d_in[23];
    const float* Wg = (const float*)d_in[24];
    const float* We1 = (const float*)d_in[25]; const float* be1 = (const float*)d_in[26];
    const float* We2 = (const float*)d_in[27]; const float* be2 = (const float*)d_in[28];
    float* out = (float*)d_out;

    const int* src = eidx;
    const int* dst = eidx + NE;

    float* bufA = (float*)d_ws;                      // xl2            [N*128]
    float* bufB = bufA + (size_t)NN * 128;           // xl1, then x3   [N*128]
    float* as1  = bufB + (size_t)NN * 128;           // [N*4]
    float* ad1  = as1 + (size_t)NN * 4;              // [N*4]
    float* as2  = ad1 + (size_t)NN * 4;              // [N]
    float* ad2  = as2 + NN;                          // [N]
    int* deg    = (int*)(ad2 + NN);                  // [N]
    int* rowptr = deg + NN;                          // [N+1]
    int* cursor = rowptr + NN + 1;                   // [N]
    int* csr    = cursor + NN;                       // [E]
    int* bsum   = csr + NE;                          // [NB_SCAN]
    int* boff   = bsum + NB_SCAN;                    // [NB_SCAN]

    hipMemsetAsync(deg, 0, NN * sizeof(int), stream);
    k_enc<<<NN / ENB, 256, 0, stream>>>(des, tweet, nprop, cprop, Wd, bd, Wt, bt, Wn, bn,
                                        Wc, bc, Wi, bi, W1, a1s, a1d, bufB, as1, ad1);
    k_deg<<<(NE + 255) / 256, 256, 0, stream>>>(dst, deg);
    k_scan1<<<NB_SCAN, 256, 0, stream>>>(deg, bsum);
    k_scan2<<<1, 512, 0, stream>>>(bsum, boff, rowptr);
    k_scan3<<<NB_SCAN, 256, 0, stream>>>(deg, boff, rowptr, cursor);
    k_fill<<<(NE + 255) / 256, 256, 0, stream>>>(src, dst, cursor, csr);
    k_gat1<<<NN / 4, 256, 0, stream>>>(bufB, as1, ad1, b1, rowptr, csr, W2, a2s, a2d,
                                       bufA, as2, ad2);
    k_gat2<<<NN / 4, 256, 0, stream>>>(bufA, as2, ad2, b2, rowptr, csr, bufB);
    k_moe<<<NN / 16, 256, 0, stream>>>(bufB, Wg, We1, be1, We2, be2, out);
}